// Round 4
// baseline (2896.657 us; speedup 1.0000x reference)
//
#include <hip/hip_runtime.h>
#include <hip/hip_bf16.h>
#include <math.h>

#define NSEQ 8192
#define DM   1024
#define HID  512
#define NB   4

// ---------------- ws layout (float offsets) ----------------
#define OFF_W1T  0u
#define SZ_W1T   (3u*1024u*512u)            // w_ctx1 repacked [k][c][o]
#define OFF_W2T  (OFF_W1T + SZ_W1T)
#define SZ_W2T   (3u*512u*512u)             // w_ctx2 repacked [k][c][o]
#define OFF_WI1T (OFF_W2T + SZ_W2T)
#define SZ_WI1T  (512u*512u)                // w_imp1 repacked [h][o]
#define OFF_Y1   (OFF_WI1T + SZ_WI1T)
#define SZ_Y     (4u*512u*8192u)
#define OFF_Y2   (OFF_Y1 + SZ_Y)
#define OFF_PLOG (OFF_Y2 + SZ_Y)
#define SZ_PLOG  (8u*32768u*2u)             // per-o-tile logit partials (DOUBLE)
#define OFF_MASK (OFF_PLOG + SZ_PLOG)
#define OFF_L    (OFF_MASK + 32768u)        // fwd scan, complex
#define OFF_R    (OFF_L + 65536u)           // bwd scan, complex
#define OFF_FEAT (OFF_R + 65536u)           // G re/im, [b][n][2]
#define OFF_SPT  (OFF_FEAT + 65536u)        // sparse transposed [b][2][n]
#define OFF_P1   (OFF_SPT + 65536u)
#define SZ_P     (4u*32u*8192u)
#define OFF_P2   (OFF_P1 + SZ_P)
#define OFF_CNT  (OFF_P2 + SZ_P)

// ---------------- utility kernels ----------------
__global__ void zero_cnt_kernel(float* cnt) {
    if (threadIdx.x == 0 && blockIdx.x == 0) *cnt = 0.f;
}

__global__ __launch_bounds__(256) void repack_kernel(
    const float* __restrict__ w1, const float* __restrict__ w2,
    const float* __restrict__ wi1,
    float* __restrict__ w1t, float* __restrict__ w2t, float* __restrict__ wi1t) {
    int idx = blockIdx.x * 256 + threadIdx.x;
    if (idx < (int)SZ_W1T) {
        int o = idx & 511, c = (idx >> 9) & 1023, k = idx >> 19;
        w1t[idx] = w1[((size_t)o * 1024 + c) * 3 + k];
    } else if (idx < (int)(SZ_W1T + SZ_W2T)) {
        int j = idx - (int)SZ_W1T;
        int o = j & 511, c = (j >> 9) & 511, k = j >> 18;
        w2t[j] = w2[((size_t)o * 512 + c) * 3 + k];
    } else if (idx < (int)(SZ_W1T + SZ_W2T + SZ_WI1T)) {
        int j = idx - (int)(SZ_W1T + SZ_W2T);
        int o = j & 511, h = j >> 9;
        wi1t[j] = wi1[(size_t)o * 512 + h];
    }
}

// ---------------- conv1/conv2: tiled GEMM with 3-tap fusion ----------------
// Accuracy scheme: fp32 accumulation within each CT=32-channel chunk, folded
// into an fp64 total per chunk. Logit error ~4e-7 abs -> mask-bit-stable vs
// the np(f64) reference (margin distribution ~8e-5), at ~fp32 FLOP rate.
// out[b][o][n] = relu( sum_{c,k} in[b][c][n+k-1] * w[o][c][k] + bias[o] )
// wt layout: [k][CIN][512].  NMAJOR: input is x[b][n][c] (c contiguous); else [b][c][n].
template<int CIN, bool NMAJOR>
__global__ __launch_bounds__(256) void conv_kernel(
    const float* __restrict__ in, const float* __restrict__ wt,
    const float* __restrict__ bias, float* __restrict__ out) {
    const int NT = 128, OT = 64, CT = 32;
    int n0 = blockIdx.x * NT, o0 = blockIdx.y * OT, b = blockIdx.z;
    __shared__ float wl[3][CT][OT];     // 24 KB
    __shared__ float xl[CT][136];       // 17 KB (130 used, padded for float4 align)
    int tid = threadIdx.x;
    int to = tid >> 4, tn = tid & 15;   // 4 o x 8 n micro-tile
    double acc[4][8];
#pragma unroll
    for (int i = 0; i < 4; i++)
#pragma unroll
        for (int j = 0; j < 8; j++) acc[i][j] = 0.0;

    for (int c0 = 0; c0 < CIN; c0 += CT) {
        for (int i = tid; i < 3 * CT * OT; i += 256) {
            int o = i & 63, c = (i >> 6) & 31, k = i >> 11;
            wl[k][c][o] = wt[((size_t)k * CIN + c0 + c) * 512 + o0 + o];
        }
        if (NMAJOR) {
            for (int i = tid; i < CT * 130; i += 256) {
                int c = i & 31, j = i >> 5;
                int n = n0 - 1 + j;
                xl[c][j] = (n >= 0 && n < NSEQ)
                    ? in[((size_t)b * NSEQ + n) * CIN + c0 + c] : 0.f;
            }
        } else {
            for (int i = tid; i < CT * 130; i += 256) {
                int j = i % 130, c = i / 130;
                int n = n0 - 1 + j;
                xl[c][j] = (n >= 0 && n < NSEQ)
                    ? in[((size_t)b * CIN + c0 + c) * NSEQ + n] : 0.f;
            }
        }
        __syncthreads();
        float cacc[4][8];
#pragma unroll
        for (int i = 0; i < 4; i++)
#pragma unroll
            for (int j = 0; j < 8; j++) cacc[i][j] = 0.f;
        for (int cc = 0; cc < CT; ++cc) {
            float xs[10];
            float4 t0 = *(const float4*)&xl[cc][8 * tn];
            float4 t1 = *(const float4*)&xl[cc][8 * tn + 4];
            xs[0] = t0.x; xs[1] = t0.y; xs[2] = t0.z; xs[3] = t0.w;
            xs[4] = t1.x; xs[5] = t1.y; xs[6] = t1.z; xs[7] = t1.w;
            xs[8] = xl[cc][8 * tn + 8];
            xs[9] = xl[cc][8 * tn + 9];
#pragma unroll
            for (int k = 0; k < 3; ++k) {
                float4 wv = *(const float4*)&wl[k][cc][4 * to];
                float wa[4] = {wv.x, wv.y, wv.z, wv.w};
#pragma unroll
                for (int i = 0; i < 4; i++)
#pragma unroll
                    for (int j = 0; j < 8; j++)
                        cacc[i][j] = fmaf(wa[i], xs[j + k], cacc[i][j]);
            }
        }
#pragma unroll
        for (int i = 0; i < 4; i++)
#pragma unroll
            for (int j = 0; j < 8; j++) acc[i][j] += (double)cacc[i][j];
        __syncthreads();
    }
#pragma unroll
    for (int i = 0; i < 4; i++) {
        int o = o0 + 4 * to + i;
        double bs = (double)bias[o];
        float r[8];
#pragma unroll
        for (int j = 0; j < 8; j++) r[j] = (float)fmax(acc[i][j] + bs, 0.0);
        size_t base = ((size_t)b * 512 + o) * NSEQ + n0 + 8 * tn;
        *(float4*)&out[base]     = make_float4(r[0], r[1], r[2], r[3]);
        *(float4*)&out[base + 4] = make_float4(r[4], r[5], r[6], r[7]);
    }
}

// ---------------- imp: hh = relu(y2^T @ wi1^T + b1); partial logits ----------
// Same fp32-chunk / fp64-total scheme; logit partials kept in fp64.
__global__ __launch_bounds__(256) void imp_kernel(
    const float* __restrict__ y2, const float* __restrict__ wt,
    const float* __restrict__ b1, const float* __restrict__ w2,
    double* __restrict__ plog) {
    const int CT = 32;
    int n0 = blockIdx.x * 64, ot = blockIdx.y, b = blockIdx.z;
    int o0 = ot * 64;
    __shared__ float wl[CT][64];
    __shared__ float xl[CT][64];
    __shared__ double red[16][64];       // 8 KB
    int tid = threadIdx.x;
    int to = tid >> 4, tn = tid & 15;
    double acc[4][4];
#pragma unroll
    for (int i = 0; i < 4; i++)
#pragma unroll
        for (int j = 0; j < 4; j++) acc[i][j] = 0.0;

    for (int c0 = 0; c0 < 512; c0 += CT) {
        for (int i = tid; i < CT * 64; i += 256) {
            int o = i & 63, c = i >> 6;
            wl[c][o] = wt[(size_t)(c0 + c) * 512 + o0 + o];
            xl[c][o] = y2[((size_t)b * 512 + c0 + c) * NSEQ + n0 + o];
        }
        __syncthreads();
        float cacc[4][4];
#pragma unroll
        for (int i = 0; i < 4; i++)
#pragma unroll
            for (int j = 0; j < 4; j++) cacc[i][j] = 0.f;
        for (int cc = 0; cc < CT; ++cc) {
            float4 wv = *(const float4*)&wl[cc][4 * to];
            float4 xv = *(const float4*)&xl[cc][4 * tn];
            float wa[4] = {wv.x, wv.y, wv.z, wv.w};
            float xa[4] = {xv.x, xv.y, xv.z, xv.w};
#pragma unroll
            for (int i = 0; i < 4; i++)
#pragma unroll
                for (int j = 0; j < 4; j++)
                    cacc[i][j] = fmaf(wa[i], xa[j], cacc[i][j]);
        }
#pragma unroll
        for (int i = 0; i < 4; i++)
#pragma unroll
            for (int j = 0; j < 4; j++) acc[i][j] += (double)cacc[i][j];
        __syncthreads();
    }
    double part[4] = {0.0, 0.0, 0.0, 0.0};
#pragma unroll
    for (int i = 0; i < 4; i++) {
        int o = o0 + 4 * to + i;
        double bb = (double)b1[o], ww = (double)w2[o];
#pragma unroll
        for (int j = 0; j < 4; j++) {
            double hh = fmax(acc[i][j] + bb, 0.0);
            part[j] = fma(hh, ww, part[j]);
        }
    }
#pragma unroll
    for (int j = 0; j < 4; j++) red[to][4 * tn + j] = part[j];
    __syncthreads();
    if (tid < 64) {
        double s = 0.0;
#pragma unroll
        for (int r = 0; r < 16; ++r) s += red[r][tid];
        plog[(size_t)ot * 32768 + (size_t)b * NSEQ + n0 + tid] = s;
    }
}

// ---------------- mask: logits -> gumbel-sigmoid hard bit (FP64 decision) ----------
__global__ __launch_bounds__(256) void mask_kernel(
    const double* __restrict__ plog, const float* __restrict__ u,
    const float* __restrict__ b2, float* __restrict__ maskf,
    float* __restrict__ cnt, float* __restrict__ outmask) {
    int bn = blockIdx.x * 256 + threadIdx.x;
    double lg = (double)b2[0];
#pragma unroll
    for (int ot = 0; ot < 8; ++ot) lg += plog[(size_t)ot * 32768 + bn];
    double uu = (double)u[bn];
    double g = -log(-log(uu + 1e-10) + 1e-10);
    double t = lg + g;                       // TAU = 1.0; sigmoid(t)>0.5 <=> t>0
    float hard = (t > 0.0) ? 1.f : 0.f;
    maskf[bn] = hard;
    outmask[bn] = hard;
    __shared__ float cs[256];
    cs[threadIdx.x] = hard;
    __syncthreads();
    for (int s = 128; s > 0; s >>= 1) {
        if (threadIdx.x < s) cs[threadIdx.x] += cs[threadIdx.x + s];
        __syncthreads();
    }
    if (threadIdx.x == 0) atomicAdd(cnt, cs[0]);   // integer-valued: exact
}

// ---------------- Green's function: segmented contractive scans ----------------
#define SEG 128
#define OV  64
__global__ __launch_bounds__(256) void green_scan_kernel(
    const float* __restrict__ v, float* __restrict__ Lb, float* __restrict__ Rb) {
    int t = blockIdx.x * 256 + threadIdx.x;      // 0..511
    int rem = t & 255;
    int b = rem >> 6, seg = rem & 63;
    int start = seg * SEG;
    const float* vb = v + (size_t)b * NSEQ;
    if (t < 256) {                               // forward: L_i = z - d_i - 1/L_{i-1}
        int wst = start - OV; if (wst < 0) wst = 0;
        float Lr = 0.f, Li = 0.f;
        for (int pos = wst; pos < start + SEG; ++pos) {
            float d = vb[pos] - 2.f;
            float nr = -d, ni = 1.f;
            if (pos > wst) {
                float inv = 1.f / (Lr * Lr + Li * Li);
                nr -= Lr * inv;
                ni += Li * inv;
            }
            Lr = nr; Li = ni;
            if (pos >= start) {
                size_t idx = (size_t)b * NSEQ + pos;
                Lb[2 * idx] = Lr; Lb[2 * idx + 1] = Li;
            }
        }
    } else {                                     // backward
        int we = start + SEG - 1 + OV; if (we > NSEQ - 1) we = NSEQ - 1;
        float Rr = 0.f, Ri = 0.f;
        for (int pos = we; pos >= start; --pos) {
            float d = vb[pos] - 2.f;
            float nr = -d, ni = 1.f;
            if (pos < we) {
                float inv = 1.f / (Rr * Rr + Ri * Ri);
                nr -= Rr * inv;
                ni += Ri * inv;
            }
            Rr = nr; Ri = ni;
            if (pos < start + SEG) {
                size_t idx = (size_t)b * NSEQ + pos;
                Rb[2 * idx] = Rr; Rb[2 * idx + 1] = Ri;
            }
        }
    }
}

__global__ __launch_bounds__(256) void combine_kernel(
    const float* __restrict__ v, const float* __restrict__ Lb,
    const float* __restrict__ Rb, const float* __restrict__ maskf,
    float* __restrict__ feat, float* __restrict__ spT) {
    int bn = blockIdx.x * 256 + threadIdx.x;
    int b = bn >> 13, n = bn & 8191;
    float d = v[bn] - 2.f;
    float dr = Lb[2 * bn] + Rb[2 * bn] + d;            // - (z-d).re = +d
    float di = Lb[2 * bn + 1] + Rb[2 * bn + 1] - 1.f;  // - (z-d).im = -1
    float inv = 1.f / (dr * dr + di * di);
    float Gre = dr * inv, Gim = -di * inv;
    feat[2 * bn] = Gre; feat[2 * bn + 1] = Gim;
    float m = maskf[bn];
    spT[((size_t)b * 2 + 0) * NSEQ + n] = Gre * m;
    spT[((size_t)b * 2 + 1) * NSEQ + n] = Gim * m;
}

// ---------------- tiny interp convs ----------------
__global__ __launch_bounds__(256) void p1_kernel(
    const float* __restrict__ spT, const float* __restrict__ w,
    const float* __restrict__ bias, float* __restrict__ p1) {
    int bn = blockIdx.x * 256 + threadIdx.x;
    int b = bn >> 13, n = bn & 8191;
    float s[2][5];
#pragma unroll
    for (int ic = 0; ic < 2; ++ic)
#pragma unroll
        for (int k = 0; k < 5; ++k) {
            int nn = n + k - 2;
            s[ic][k] = (nn >= 0 && nn < NSEQ) ? spT[((size_t)b * 2 + ic) * NSEQ + nn] : 0.f;
        }
#pragma unroll
    for (int oc = 0; oc < 32; ++oc) {
        float a = bias[oc];
#pragma unroll
        for (int ic = 0; ic < 2; ++ic)
#pragma unroll
            for (int k = 0; k < 5; ++k)
                a = fmaf(s[ic][k], w[(oc * 2 + ic) * 5 + k], a);
        p1[((size_t)b * 32 + oc) * NSEQ + n] = fmaxf(a, 0.f);
    }
}

__global__ __launch_bounds__(256) void p2_kernel(
    const float* __restrict__ p1, const float* __restrict__ w,
    const float* __restrict__ bias, float* __restrict__ p2) {
    int bn = blockIdx.x * 256 + threadIdx.x;
    int b = bn >> 13, n = bn & 8191;
    float acc[32];
#pragma unroll
    for (int oc = 0; oc < 32; ++oc) acc[oc] = bias[oc];
    for (int ic = 0; ic < 32; ++ic) {
        float s[5];
#pragma unroll
        for (int k = 0; k < 5; ++k) {
            int nn = n + k - 2;
            s[k] = (nn >= 0 && nn < NSEQ) ? p1[((size_t)b * 32 + ic) * NSEQ + nn] : 0.f;
        }
#pragma unroll
        for (int oc = 0; oc < 32; ++oc)
#pragma unroll
            for (int k = 0; k < 5; ++k)
                acc[oc] = fmaf(s[k], w[(oc * 32 + ic) * 5 + k], acc[oc]);
    }
#pragma unroll
    for (int oc = 0; oc < 32; ++oc)
        p2[((size_t)b * 32 + oc) * NSEQ + n] = fmaxf(acc[oc], 0.f);
}

__global__ __launch_bounds__(256) void p3_final_kernel(
    const float* __restrict__ p2, const float* __restrict__ w,
    const float* __restrict__ bias, const float* __restrict__ feat,
    const float* __restrict__ maskf, float* __restrict__ out) {
    int bn = blockIdx.x * 256 + threadIdx.x;
    int b = bn >> 13, n = bn & 8191;
    float a0 = bias[0], a1 = bias[1];
    for (int ic = 0; ic < 32; ++ic) {
#pragma unroll
        for (int k = 0; k < 5; ++k) {
            int nn = n + k - 2;
            float s = (nn >= 0 && nn < NSEQ) ? p2[((size_t)b * 32 + ic) * NSEQ + nn] : 0.f;
            a0 = fmaf(s, w[(0 * 32 + ic) * 5 + k], a0);
            a1 = fmaf(s, w[(1 * 32 + ic) * 5 + k], a1);
        }
    }
    float m = maskf[bn];
    float f0 = feat[2 * bn], f1 = feat[2 * bn + 1];
    // mask==1 -> sparse = feat*1 = feat; mask==0 -> interp
    out[2 * bn]     = (m > 0.5f) ? f0 : a0;
    out[2 * bn + 1] = (m > 0.5f) ? f1 : a1;
}

__global__ void sparsity_kernel(const float* __restrict__ cnt, float* __restrict__ out) {
    if (threadIdx.x == 0 && blockIdx.x == 0)
        out[0] = 1.f - (*cnt) * (1.f / 32768.f);
}

// ---------------- launch ----------------
extern "C" void kernel_launch(void* const* d_in, const int* in_sizes, int n_in,
                              void* d_out, int out_size, void* d_ws, size_t ws_size,
                              hipStream_t stream) {
    (void)in_sizes; (void)n_in; (void)out_size; (void)ws_size;
    const float* x      = (const float*)d_in[0];
    const float* v      = (const float*)d_in[1];
    const float* u      = (const float*)d_in[2];
    const float* w_ctx1 = (const float*)d_in[3];
    const float* b_ctx1 = (const float*)d_in[4];
    const float* w_ctx2 = (const float*)d_in[5];
    const float* b_ctx2 = (const float*)d_in[6];
    const float* w_imp1 = (const float*)d_in[7];
    const float* b_imp1 = (const float*)d_in[8];
    const float* w_imp2 = (const float*)d_in[9];
    const float* b_imp2 = (const float*)d_in[10];
    const float* w_int1 = (const float*)d_in[11];
    const float* b_int1 = (const float*)d_in[12];
    const float* w_int2 = (const float*)d_in[13];
    const float* b_int2 = (const float*)d_in[14];
    const float* w_int3 = (const float*)d_in[15];
    const float* b_int3 = (const float*)d_in[16];
    float* ws = (float*)d_ws;
    float* out = (float*)d_out;           // reference outputs are float32

    float*  w1t   = ws + OFF_W1T;
    float*  w2t   = ws + OFF_W2T;
    float*  wi1t  = ws + OFF_WI1T;
    float*  y1    = ws + OFF_Y1;
    float*  y2    = ws + OFF_Y2;
    double* plog  = (double*)(ws + OFF_PLOG);
    float*  maskf = ws + OFF_MASK;
    float*  Lb    = ws + OFF_L;
    float*  Rb    = ws + OFF_R;
    float*  feat  = ws + OFF_FEAT;
    float*  spT   = ws + OFF_SPT;
    float*  p1    = ws + OFF_P1;
    float*  p2    = ws + OFF_P2;
    float*  cnt   = ws + OFF_CNT;

    zero_cnt_kernel<<<1, 64, 0, stream>>>(cnt);
    repack_kernel<<<(int)((SZ_W1T + SZ_W2T + SZ_WI1T + 255) / 256), 256, 0, stream>>>(
        w_ctx1, w_ctx2, w_imp1, w1t, w2t, wi1t);

    dim3 gc(64, 8, 4);   // 8192/128 n-tiles, 512/64 o-tiles, B
    conv_kernel<1024, true ><<<gc, 256, 0, stream>>>(x,  w1t, b_ctx1, y1);
    conv_kernel< 512, false><<<gc, 256, 0, stream>>>(y1, w2t, b_ctx2, y2);

    dim3 gi(128, 8, 4);  // 8192/64 n-tiles
    imp_kernel<<<gi, 256, 0, stream>>>(y2, wi1t, b_imp1, w_imp2, plog);

    green_scan_kernel<<<2, 256, 0, stream>>>(v, Lb, Rb);
    mask_kernel<<<128, 256, 0, stream>>>(plog, u, b_imp2, maskf, cnt, out + 65536);
    combine_kernel<<<128, 256, 0, stream>>>(v, Lb, Rb, maskf, feat, spT);
    p1_kernel<<<128, 256, 0, stream>>>(spT, w_int1, b_int1, p1);
    p2_kernel<<<128, 256, 0, stream>>>(p1, w_int2, b_int2, p2);
    p3_final_kernel<<<128, 256, 0, stream>>>(p2, w_int3, b_int3, feat, maskf, out);
    sparsity_kernel<<<1, 64, 0, stream>>>(cnt, out + 98304);
}